// Round 2
// 109.934 us; speedup vs baseline: 1.0124x; 1.0124x over previous
//
#include <hip/hip_runtime.h>

#define BATCH 32768
#define FEAT  512
#define NCLS  1000
#define CAP   256   // max samples/class kept in LDS. Poisson(mean 32.8): P(>256) ~ 0.

typedef float v4f __attribute__((ext_vector_type(4)));

// One block per class, 512 threads (8 waves).
// Phase 1: all threads scan the 32768 labels (int4 loads, L2-resident after the
//          first blocks) and append matching sample indices to an LDS list via
//          shared-memory atomics. This replaces the separate scatter kernel, the
//          counts memset, and the global counts/slots workspace round-trip.
// Phase 2: 4 subgroups x 128 float4-columns. Subgroup s handles samples
//          s, s+4, s+8, ... with 2-deep load batching; columns are
//          thread-exclusive so the center update needs no reduction.
// Phase 3: combine the 4 subgroup partial sums through LDS; subgroup 0 writes
//          the new center. Loss: per-wave shuffle reduce -> LDS -> one
//          atomicAdd per block onto out[0] (zeroed by a 4-byte memset).
__global__ __launch_bounds__(512, 4) void cl_fused(
    const float* __restrict__ feats, const int* __restrict__ labels,
    const float* __restrict__ centers, float* __restrict__ out)
{
    const int tid  = threadIdx.x;
    const int cls  = blockIdx.x;
    const int sub  = tid >> 7;           // subgroup 0..3 -> sample parity
    const int col4 = tid & 127;          // float4 column [0,128)

    __shared__ int   cnt;
    __shared__ int   list[CAP];
    __shared__ v4f   red[3][128];        // partial sums from subgroups 1..3
    __shared__ float lred[8];            // per-wave loss partials

    if (tid == 0) cnt = 0;

    // center fragment for this lane's 4 columns (issue early, overlaps scan)
    const v4f c = reinterpret_cast<const v4f*>(centers)[cls * 128 + col4];
    __syncthreads();

    // ---- phase 1: label scan -> LDS sample list ----
    const int4* __restrict__ lab4 = reinterpret_cast<const int4*>(labels);
    for (int it = tid; it < BATCH / 4; it += 512) {      // 16 iterations exactly
        const int4 L = lab4[it];
        const int b = it * 4;
        if (L.x == cls) { const int p = atomicAdd(&cnt, 1); if (p < CAP) list[p] = b;     }
        if (L.y == cls) { const int p = atomicAdd(&cnt, 1); if (p < CAP) list[p] = b + 1; }
        if (L.z == cls) { const int p = atomicAdd(&cnt, 1); if (p < CAP) list[p] = b + 2; }
        if (L.w == cls) { const int p = atomicAdd(&cnt, 1); if (p < CAP) list[p] = b + 3; }
    }
    __syncthreads();
    int n = cnt;
    if (n > CAP) n = CAP;

    // ---- phase 2: gather feature rows, accumulate sum + loss ----
    const v4f* __restrict__ f4 = reinterpret_cast<const v4f*>(feats);
    v4f acc = {0.f, 0.f, 0.f, 0.f};
    float lsum = 0.f;

    int i = sub;
    for (; i + 4 < n; i += 8) {          // two samples in flight per thread
        const int s0 = list[i], s1 = list[i + 4];
        const v4f f0 = f4[s0 * 128 + col4];
        const v4f f1 = f4[s1 * 128 + col4];
        acc += f0 + f1;
        v4f d = f0 - c; lsum += d.x * d.x + d.y * d.y + d.z * d.z + d.w * d.w;
        d     = f1 - c; lsum += d.x * d.x + d.y * d.y + d.z * d.z + d.w * d.w;
    }
    if (i < n) {                         // per-subgroup tail (0 or 1 sample)
        const v4f f = f4[list[i] * 128 + col4];
        acc += f;
        const v4f d = f - c;
        lsum += d.x * d.x + d.y * d.y + d.z * d.z + d.w * d.w;
    }

    // ---- phase 3: combine subgroups, write center + loss ----
    if (sub) red[sub - 1][col4] = acc;

    #pragma unroll
    for (int off = 32; off; off >>= 1) lsum += __shfl_down(lsum, off, 64);
    if ((tid & 63) == 0) lred[tid >> 6] = lsum;

    __syncthreads();

    if (sub == 0) {
        v4f t = acc + red[0][col4] + red[1][col4] + red[2][col4];
        v4f nc = c;
        if (n > 0) {
            const float inv = 1.f / (float)n;
            nc.x = 0.5f * c.x + 0.5f * t.x * inv;
            nc.y = 0.5f * c.y + 0.5f * t.y * inv;
            nc.z = 0.5f * c.z + 0.5f * t.z * inv;
            nc.w = 0.5f * c.w + 0.5f * t.w * inv;
        }
        const int base = 1 + cls * FEAT + col4 * 4;   // out+1 is float4-misaligned
        out[base + 0] = nc.x; out[base + 1] = nc.y;
        out[base + 2] = nc.z; out[base + 3] = nc.w;
    }

    if (tid == 0) {
        const float t = lred[0] + lred[1] + lred[2] + lred[3] +
                        lred[4] + lred[5] + lred[6] + lred[7];
        atomicAdd(out, t * (0.5f / (float)BATCH));
    }
}

extern "C" void kernel_launch(void* const* d_in, const int* in_sizes, int n_in,
                              void* d_out, int out_size, void* d_ws, size_t ws_size,
                              hipStream_t stream) {
    const float* feats   = (const float*)d_in[0];
    const int*   labels  = (const int*)d_in[1];
    const float* centers = (const float*)d_in[2];
    float* out = (float*)d_out;

    hipMemsetAsync(d_out, 0, sizeof(float), stream);   // loss accumulator only
    cl_fused<<<NCLS, 512, 0, stream>>>(feats, labels, centers, out);
}

// Round 3
// 107.938 us; speedup vs baseline: 1.0311x; 1.0185x over previous
//
#include <hip/hip_runtime.h>

#define BATCH 32768
#define FEAT  512
#define NCLS  1000
#define CAP   256   // max samples/class in LDS. Poisson(mean 32.8): P(>256) ~ 0.

typedef float v4f __attribute__((ext_vector_type(4)));

// One block per 2 classes, 512 threads (8 waves), 500 blocks.
// Phase 1: all threads scan the 32768 labels (int4 loads, L2-resident after the
//          first blocks) testing against BOTH classes -> two LDS sample lists.
//          2 classes/block halves the redundant label traffic (128->64 MB L2)
//          at identical total compare work.
// Phase 2: 4 subgroups x 128 float4-columns; subgroups (2 per class) split the
//          sample list even/odd with 4-deep load batching (4x16B in flight per
//          thread). Columns are thread-exclusive so the center needs no
//          cross-column reduction, only a 2-way half combine through LDS.
// Phase 3: half 0 writes the new center; loss via per-wave shuffle reduce ->
//          LDS -> one atomicAdd per block onto out[0] (zeroed by 4-byte memset).
__global__ __launch_bounds__(512, 4) void cl_fused(
    const float* __restrict__ feats, const int* __restrict__ labels,
    const float* __restrict__ centers, float* __restrict__ out)
{
    const int tid  = threadIdx.x;
    const int sub  = tid >> 7;           // subgroup 0..3
    const int ci   = sub >> 1;           // class slot 0/1
    const int h    = sub & 1;            // half within class: even/odd samples
    const int col4 = tid & 127;          // float4 column [0,128)
    const int clsA = blockIdx.x * 2;
    const int clsB = clsA + 1;
    const int cls  = clsA + ci;

    __shared__ int   cnt[2];
    __shared__ int   list[2][CAP];
    __shared__ v4f   red[2][128];        // half-1 partial sums per class
    __shared__ float lred[8];            // per-wave loss partials

    if (tid < 2) cnt[tid] = 0;

    // center fragment for this lane's class+columns (issue early, overlaps scan)
    const v4f c = reinterpret_cast<const v4f*>(centers)[cls * 128 + col4];
    __syncthreads();

    // ---- phase 1: label scan -> LDS sample lists for both classes ----
    const int4* __restrict__ lab4 = reinterpret_cast<const int4*>(labels);
    for (int it = tid; it < BATCH / 4; it += 512) {      // 16 iterations exactly
        const int4 L = lab4[it];
        const int b = it * 4;
#define CL_TEST(V, OFF) \
        if ((V) == clsA)      { const int p = atomicAdd(&cnt[0], 1); if (p < CAP) list[0][p] = b + (OFF); } \
        else if ((V) == clsB) { const int p = atomicAdd(&cnt[1], 1); if (p < CAP) list[1][p] = b + (OFF); }
        CL_TEST(L.x, 0)
        CL_TEST(L.y, 1)
        CL_TEST(L.z, 2)
        CL_TEST(L.w, 3)
#undef CL_TEST
    }
    __syncthreads();
    int n = cnt[ci];
    if (n > CAP) n = CAP;
    const int* __restrict__ lst = list[ci];

    // ---- phase 2: gather feature rows, accumulate sum + loss (4-deep) ----
    const v4f* __restrict__ f4 = reinterpret_cast<const v4f*>(feats);
    v4f acc = {0.f, 0.f, 0.f, 0.f};
    float lsum = 0.f;

    int i = h;                            // half h owns samples h, h+2, h+4, ...
    for (; i + 6 < n; i += 8) {           // 4 samples in flight per thread
        const int s0 = lst[i], s1 = lst[i + 2], s2 = lst[i + 4], s3 = lst[i + 6];
        const v4f f0 = f4[s0 * 128 + col4];
        const v4f f1 = f4[s1 * 128 + col4];
        const v4f f2 = f4[s2 * 128 + col4];
        const v4f f3 = f4[s3 * 128 + col4];
        acc += f0 + f1 + f2 + f3;
        v4f d;
        d = f0 - c; lsum += d.x * d.x + d.y * d.y + d.z * d.z + d.w * d.w;
        d = f1 - c; lsum += d.x * d.x + d.y * d.y + d.z * d.z + d.w * d.w;
        d = f2 - c; lsum += d.x * d.x + d.y * d.y + d.z * d.z + d.w * d.w;
        d = f3 - c; lsum += d.x * d.x + d.y * d.y + d.z * d.z + d.w * d.w;
    }
    for (; i < n; i += 2) {               // tail: 0..3 samples for this half
        const v4f f = f4[lst[i] * 128 + col4];
        acc += f;
        const v4f d = f - c;
        lsum += d.x * d.x + d.y * d.y + d.z * d.z + d.w * d.w;
    }

    // ---- phase 3: combine halves, write center + loss ----
    if (h) red[ci][col4] = acc;

    #pragma unroll
    for (int off = 32; off; off >>= 1) lsum += __shfl_down(lsum, off, 64);
    if ((tid & 63) == 0) lred[tid >> 6] = lsum;

    __syncthreads();

    if (!h) {
        v4f t = acc + red[ci][col4];
        v4f nc = c;
        if (n > 0) {
            const float inv = 1.f / (float)n;
            nc.x = 0.5f * c.x + 0.5f * t.x * inv;
            nc.y = 0.5f * c.y + 0.5f * t.y * inv;
            nc.z = 0.5f * c.z + 0.5f * t.z * inv;
            nc.w = 0.5f * c.w + 0.5f * t.w * inv;
        }
        const int base = 1 + cls * FEAT + col4 * 4;   // out+1 is float4-misaligned
        out[base + 0] = nc.x; out[base + 1] = nc.y;
        out[base + 2] = nc.z; out[base + 3] = nc.w;
    }

    if (tid == 0) {
        const float t = lred[0] + lred[1] + lred[2] + lred[3] +
                        lred[4] + lred[5] + lred[6] + lred[7];
        atomicAdd(out, t * (0.5f / (float)BATCH));
    }
}

extern "C" void kernel_launch(void* const* d_in, const int* in_sizes, int n_in,
                              void* d_out, int out_size, void* d_ws, size_t ws_size,
                              hipStream_t stream) {
    const float* feats   = (const float*)d_in[0];
    const int*   labels  = (const int*)d_in[1];
    const float* centers = (const float*)d_in[2];
    float* out = (float*)d_out;

    hipMemsetAsync(d_out, 0, sizeof(float), stream);   // loss accumulator only
    cl_fused<<<NCLS / 2, 512, 0, stream>>>(feats, labels, centers, out);
}

// Round 4
// 104.043 us; speedup vs baseline: 1.0697x; 1.0374x over previous
//
#include <hip/hip_runtime.h>

#define BATCH 32768
#define FEAT  512
#define NCLS  1000
#define CAP   256   // max samples/class in LDS. Poisson(mean 32.8): P(>256) ~ 0.

typedef float v4f __attribute__((ext_vector_type(4)));

// One block per 2 classes, 512 threads (8 waves), 500 blocks.
// No memset dispatch: block 0 zeroes the loss word via device-scope atomicExch
// at kernel entry. Safety: block 0 is first in the CP dispatch sequence and the
// earliest possible loss atomicAdd from any block sits >=1.5us of scan+gather
// after that block's start vs ~0.1us for block 0 to issue the exch.
// Phase 1: all threads scan the 32768 labels with 4-deep int4 load batching
//          (cuts 16 serialized L2 round trips to ~4 groups), testing against
//          both classes -> two LDS sample lists via LDS atomics.
// Phase 2: 4 subgroups x 128 float4-columns; 2 subgroups per class split the
//          sample list even/odd, 4-deep load batching (4x16B in flight/thread).
//          Columns are thread-exclusive: center update needs only a 2-way
//          half-combine through LDS, no cross-column reduction.
// Phase 3: half 0 writes the new center; loss via per-wave shuffle reduce ->
//          LDS -> one atomicAdd per block onto out[0].
__global__ __launch_bounds__(512, 4) void cl_fused(
    const float* __restrict__ feats, const int* __restrict__ labels,
    const float* __restrict__ centers, float* __restrict__ out)
{
    const int tid  = threadIdx.x;
    const int sub  = tid >> 7;           // subgroup 0..3
    const int ci   = sub >> 1;           // class slot 0/1
    const int h    = sub & 1;            // half within class: even/odd samples
    const int col4 = tid & 127;          // float4 column [0,128)
    const int clsA = blockIdx.x * 2;
    const int clsB = clsA + 1;
    const int cls  = clsA + ci;

    if (blockIdx.x == 0 && tid == 0) atomicExch(out, 0.f);  // zero loss word

    __shared__ int   cnt[2];
    __shared__ int   list[2][CAP];
    __shared__ v4f   red[2][128];        // half-1 partial sums per class
    __shared__ float lred[8];            // per-wave loss partials

    if (tid < 2) cnt[tid] = 0;

    // center fragment for this lane's class+columns (issue early, overlaps scan)
    const v4f c = reinterpret_cast<const v4f*>(centers)[cls * 128 + col4];
    __syncthreads();

    // ---- phase 1: 4-deep batched label scan -> LDS sample lists ----
    const int4* __restrict__ lab4 = reinterpret_cast<const int4*>(labels);
#define CL_TEST(V, B) \
        if ((V) == clsA)      { const int p = atomicAdd(&cnt[0], 1); if (p < CAP) list[0][p] = (B); } \
        else if ((V) == clsB) { const int p = atomicAdd(&cnt[1], 1); if (p < CAP) list[1][p] = (B); }
    #pragma unroll
    for (int o = 0; o < 16; o += 4) {    // 16 int4 iterations, 4 loads in flight
        const int i0 = tid + (o + 0) * 512;
        const int i1 = tid + (o + 1) * 512;
        const int i2 = tid + (o + 2) * 512;
        const int i3 = tid + (o + 3) * 512;
        const int4 La = lab4[i0];
        const int4 Lb = lab4[i1];
        const int4 Lc = lab4[i2];
        const int4 Ld = lab4[i3];
        int b;
        b = i0 * 4; CL_TEST(La.x, b) CL_TEST(La.y, b + 1) CL_TEST(La.z, b + 2) CL_TEST(La.w, b + 3)
        b = i1 * 4; CL_TEST(Lb.x, b) CL_TEST(Lb.y, b + 1) CL_TEST(Lb.z, b + 2) CL_TEST(Lb.w, b + 3)
        b = i2 * 4; CL_TEST(Lc.x, b) CL_TEST(Lc.y, b + 1) CL_TEST(Lc.z, b + 2) CL_TEST(Lc.w, b + 3)
        b = i3 * 4; CL_TEST(Ld.x, b) CL_TEST(Ld.y, b + 1) CL_TEST(Ld.z, b + 2) CL_TEST(Ld.w, b + 3)
    }
#undef CL_TEST
    __syncthreads();
    int n = cnt[ci];
    if (n > CAP) n = CAP;
    const int* __restrict__ lst = list[ci];

    // ---- phase 2: gather feature rows, accumulate sum + loss (4-deep) ----
    const v4f* __restrict__ f4 = reinterpret_cast<const v4f*>(feats);
    v4f acc = {0.f, 0.f, 0.f, 0.f};
    float lsum = 0.f;

    int i = h;                            // half h owns samples h, h+2, h+4, ...
    for (; i + 6 < n; i += 8) {           // 4 samples in flight per thread
        const int s0 = lst[i], s1 = lst[i + 2], s2 = lst[i + 4], s3 = lst[i + 6];
        const v4f f0 = f4[s0 * 128 + col4];
        const v4f f1 = f4[s1 * 128 + col4];
        const v4f f2 = f4[s2 * 128 + col4];
        const v4f f3 = f4[s3 * 128 + col4];
        acc += f0 + f1 + f2 + f3;
        v4f d;
        d = f0 - c; lsum += d.x * d.x + d.y * d.y + d.z * d.z + d.w * d.w;
        d = f1 - c; lsum += d.x * d.x + d.y * d.y + d.z * d.z + d.w * d.w;
        d = f2 - c; lsum += d.x * d.x + d.y * d.y + d.z * d.z + d.w * d.w;
        d = f3 - c; lsum += d.x * d.x + d.y * d.y + d.z * d.z + d.w * d.w;
    }
    for (; i < n; i += 2) {               // tail: 0..3 samples for this half
        const v4f f = f4[lst[i] * 128 + col4];
        acc += f;
        const v4f d = f - c;
        lsum += d.x * d.x + d.y * d.y + d.z * d.z + d.w * d.w;
    }

    // ---- phase 3: combine halves, write center + loss ----
    if (h) red[ci][col4] = acc;

    #pragma unroll
    for (int off = 32; off; off >>= 1) lsum += __shfl_down(lsum, off, 64);
    if ((tid & 63) == 0) lred[tid >> 6] = lsum;

    __syncthreads();

    if (!h) {
        v4f t = acc + red[ci][col4];
        v4f nc = c;
        if (n > 0) {
            const float inv = 1.f / (float)n;
            nc.x = 0.5f * c.x + 0.5f * t.x * inv;
            nc.y = 0.5f * c.y + 0.5f * t.y * inv;
            nc.z = 0.5f * c.z + 0.5f * t.z * inv;
            nc.w = 0.5f * c.w + 0.5f * t.w * inv;
        }
        const int base = 1 + cls * FEAT + col4 * 4;   // out+1 is float4-misaligned
        out[base + 0] = nc.x; out[base + 1] = nc.y;
        out[base + 2] = nc.z; out[base + 3] = nc.w;
    }

    if (tid == 0) {
        const float t = lred[0] + lred[1] + lred[2] + lred[3] +
                        lred[4] + lred[5] + lred[6] + lred[7];
        atomicAdd(out, t * (0.5f / (float)BATCH));
    }
}

extern "C" void kernel_launch(void* const* d_in, const int* in_sizes, int n_in,
                              void* d_out, int out_size, void* d_ws, size_t ws_size,
                              hipStream_t stream) {
    const float* feats   = (const float*)d_in[0];
    const int*   labels  = (const int*)d_in[1];
    const float* centers = (const float*)d_in[2];
    float* out = (float*)d_out;

    cl_fused<<<NCLS / 2, 512, 0, stream>>>(feats, labels, centers, out);
}

// Round 5
// 97.333 us; speedup vs baseline: 1.1435x; 1.0689x over previous
//
#include <hip/hip_runtime.h>

#define BATCH 32768
#define FEAT  512
#define NCLS  1000
#define CAP   256   // max samples/class in LDS. Poisson(mean 32.8): P(>256) ~ 0.

typedef float v4f __attribute__((ext_vector_type(4)));

// One block per 4 classes, 1024 threads (16 waves), 250 blocks (all resident:
// 16 waves/block, grid < CU count). vs the 2-class/512-thread version this
// halves the redundant label-scan L2 traffic (64->32 MB) and halves each
// thread's serialized scan chain (16 -> 8 int4 L2 round trips).
// No memset dispatch: block 0 zeroes the loss word via device-scope atomicExch
// at entry; every block's loss atomicAdd sits >=1.5us of scan+gather+reduce
// after its own start vs ~0.1us for the exch to issue.
// Phase 1: all threads scan the 32768 labels (4-deep int4 batching); per label
//          one subtract + unsigned compare selects among this block's 4
//          classes -> LDS sample lists via LDS atomics.
// Phase 2: 8 subgroups x 128 float4-columns; 2 subgroups per class split that
//          class's list even/odd with 4-deep load batching (4x16B in
//          flight/thread). Columns are thread-exclusive: the center update
//          needs only a 2-way half-combine through LDS.
// Phase 3: half 0 writes the new center; loss via per-wave shuffle reduce ->
//          LDS -> one atomicAdd per block onto out[0].
__global__ __launch_bounds__(1024, 4) void cl_fused(
    const float* __restrict__ feats, const int* __restrict__ labels,
    const float* __restrict__ centers, float* __restrict__ out)
{
    const int tid     = threadIdx.x;
    const int sub     = tid >> 7;        // subgroup 0..7
    const int ci      = sub >> 1;        // class slot 0..3
    const int h       = sub & 1;         // half within class: even/odd samples
    const int col4    = tid & 127;       // float4 column [0,128)
    const int clsBase = blockIdx.x * 4;
    const int cls     = clsBase + ci;

    if (blockIdx.x == 0 && tid == 0) atomicExch(out, 0.f);  // zero loss word

    __shared__ int   cnt[4];
    __shared__ int   list[4][CAP];
    __shared__ v4f   red[4][128];        // half-1 partial sums per class
    __shared__ float lred[16];           // per-wave loss partials

    if (tid < 4) cnt[tid] = 0;

    // center fragment for this lane's class+columns (issue early, overlaps scan)
    const v4f c = reinterpret_cast<const v4f*>(centers)[cls * 128 + col4];
    __syncthreads();

    // ---- phase 1: 4-deep batched label scan -> LDS sample lists ----
    const int4* __restrict__ lab4 = reinterpret_cast<const int4*>(labels);
#define CL_TEST(V, B) { \
        const unsigned dd = (unsigned)((V) - clsBase); \
        if (dd < 4u) { const int p = atomicAdd(&cnt[dd], 1); if (p < CAP) list[dd][p] = (B); } }
    #pragma unroll
    for (int o = 0; o < 8; o += 4) {     // 8 int4 iterations, 4 loads in flight
        const int i0 = tid + (o + 0) * 1024;
        const int i1 = tid + (o + 1) * 1024;
        const int i2 = tid + (o + 2) * 1024;
        const int i3 = tid + (o + 3) * 1024;
        const int4 La = lab4[i0];
        const int4 Lb = lab4[i1];
        const int4 Lc = lab4[i2];
        const int4 Ld = lab4[i3];
        int b;
        b = i0 * 4; CL_TEST(La.x, b) CL_TEST(La.y, b + 1) CL_TEST(La.z, b + 2) CL_TEST(La.w, b + 3)
        b = i1 * 4; CL_TEST(Lb.x, b) CL_TEST(Lb.y, b + 1) CL_TEST(Lb.z, b + 2) CL_TEST(Lb.w, b + 3)
        b = i2 * 4; CL_TEST(Lc.x, b) CL_TEST(Lc.y, b + 1) CL_TEST(Lc.z, b + 2) CL_TEST(Lc.w, b + 3)
        b = i3 * 4; CL_TEST(Ld.x, b) CL_TEST(Ld.y, b + 1) CL_TEST(Ld.z, b + 2) CL_TEST(Ld.w, b + 3)
    }
#undef CL_TEST
    __syncthreads();
    int n = cnt[ci];
    if (n > CAP) n = CAP;
    const int* __restrict__ lst = list[ci];

    // ---- phase 2: gather feature rows, accumulate sum + loss (4-deep) ----
    const v4f* __restrict__ f4 = reinterpret_cast<const v4f*>(feats);
    v4f acc = {0.f, 0.f, 0.f, 0.f};
    float lsum = 0.f;

    int i = h;                            // half h owns samples h, h+2, h+4, ...
    for (; i + 6 < n; i += 8) {           // 4 samples in flight per thread
        const int s0 = lst[i], s1 = lst[i + 2], s2 = lst[i + 4], s3 = lst[i + 6];
        const v4f f0 = f4[s0 * 128 + col4];
        const v4f f1 = f4[s1 * 128 + col4];
        const v4f f2 = f4[s2 * 128 + col4];
        const v4f f3 = f4[s3 * 128 + col4];
        acc += f0 + f1 + f2 + f3;
        v4f d;
        d = f0 - c; lsum += d.x * d.x + d.y * d.y + d.z * d.z + d.w * d.w;
        d = f1 - c; lsum += d.x * d.x + d.y * d.y + d.z * d.z + d.w * d.w;
        d = f2 - c; lsum += d.x * d.x + d.y * d.y + d.z * d.z + d.w * d.w;
        d = f3 - c; lsum += d.x * d.x + d.y * d.y + d.z * d.z + d.w * d.w;
    }
    for (; i < n; i += 2) {               // tail: 0..3 samples for this half
        const v4f f = f4[lst[i] * 128 + col4];
        acc += f;
        const v4f d = f - c;
        lsum += d.x * d.x + d.y * d.y + d.z * d.z + d.w * d.w;
    }

    // ---- phase 3: combine halves, write center + loss ----
    if (h) red[ci][col4] = acc;

    #pragma unroll
    for (int off = 32; off; off >>= 1) lsum += __shfl_down(lsum, off, 64);
    if ((tid & 63) == 0) lred[tid >> 6] = lsum;

    __syncthreads();

    if (!h) {
        v4f t = acc + red[ci][col4];
        v4f nc = c;
        if (n > 0) {
            const float inv = 1.f / (float)n;
            nc.x = 0.5f * c.x + 0.5f * t.x * inv;
            nc.y = 0.5f * c.y + 0.5f * t.y * inv;
            nc.z = 0.5f * c.z + 0.5f * t.z * inv;
            nc.w = 0.5f * c.w + 0.5f * t.w * inv;
        }
        const int base = 1 + cls * FEAT + col4 * 4;   // out+1 is float4-misaligned
        out[base + 0] = nc.x; out[base + 1] = nc.y;
        out[base + 2] = nc.z; out[base + 3] = nc.w;
    }

    if (tid == 0) {
        float t = 0.f;
        #pragma unroll
        for (int w = 0; w < 16; ++w) t += lred[w];
        atomicAdd(out, t * (0.5f / (float)BATCH));
    }
}

extern "C" void kernel_launch(void* const* d_in, const int* in_sizes, int n_in,
                              void* d_out, int out_size, void* d_ws, size_t ws_size,
                              hipStream_t stream) {
    const float* feats   = (const float*)d_in[0];
    const int*   labels  = (const int*)d_in[1];
    const float* centers = (const float*)d_in[2];
    float* out = (float*)d_out;

    cl_fused<<<NCLS / 4, 1024, 0, stream>>>(feats, labels, centers, out);
}